// Round 9
// baseline (52.316 us; speedup 1.0000x reference)
//
#include <hip/hip_runtime.h>
#include <math.h>

#define BB 4
#define NN 2048
#define MM 128
#define DD 64
#define NEG_SLOPE 0.2f

#define CH  32                // n per block
#define NCH (NN / CH)         // 64 chunks
#define MW  32                // m per block
#define NMT (MM / MW)         // 4 m-tiles
#define PSTR 36               // p_lds row stride (36 floats = 144B, 16B-aligned)

// ---------------------------------------------------------------------------
// K1: per (ch, mt, b) block (1024 blocks, 256 thr, 4 blocks/CU):
//   phase0: stage fs chunk -> LDS; W_src -> 64 VGPR; u_r; c_e
//   phase1: hs = fs @ W_src^T in place (8 rows/wave, 2 batches); el; er(32 m)
//   phase2: scores p=exp(masked leaky) for 32n x 32m
//   phase3: agg acc[8m x 1d] over 32 n -> pacc; denom/sfe -> pdn
// ---------------------------------------------------------------------------
__global__ __launch_bounds__(256, 4) void fused_all_kernel(
        const float* __restrict__ fs, const float* __restrict__ W_src,
        const float* __restrict__ attn_l,
        const float* __restrict__ fd, const float* __restrict__ W_dst,
        const float* __restrict__ attn_r,
        const float* __restrict__ W_edge, const float* __restrict__ attn_e,
        const float* __restrict__ fe, const int* __restrict__ adj,
        float* __restrict__ pacc, float* __restrict__ pdn) {
    int ch = blockIdx.x, mt = blockIdx.y, b = blockIdx.z;
    int n0 = ch * CH, m0 = mt * MW;
    int t = threadIdx.x, lane = t & 63, g = t >> 6;

    __shared__ __align__(16) float fsh[CH * DD];       // 8 KB: fs then hs
    __shared__ __align__(16) float p_lds[CH * PSTR];   // 4.6 KB
    __shared__ float el_lds[CH];
    __shared__ float er_lds[MW];
    __shared__ __align__(16) float u_r[DD];
    __shared__ float dred[8][MW + 1], fred[8][MW + 1];
    __shared__ float ce_s;

    // ---- phase 0 ----
    const float4* fs4 = (const float4*)(fs + ((size_t)(b * NN + n0)) * DD);
    ((float4*)fsh)[t] = fs4[t];
    ((float4*)fsh)[t + 256] = fs4[t + 256];

    float4 wreg[16];
    const float4* w4 = (const float4*)(W_src + (size_t)lane * DD);
#pragma unroll
    for (int k = 0; k < 16; ++k) wreg[k] = w4[k];
    float al = attn_l[lane];

    if (t < 64) {                        // u_r[t] = sum_d attn_r[d]*W_dst[d,t]
        float a = 0.f;
#pragma unroll 8
        for (int dd = 0; dd < DD; ++dd) a += attn_r[dd] * W_dst[dd * DD + t];
        u_r[t] = a;
    } else if (t < 128) {                // c_e (wave 1)
        float v = W_edge[lane] * attn_e[lane];
#pragma unroll
        for (int off = 32; off > 0; off >>= 1) v += __shfl_xor(v, off, 64);
        if (lane == 0) ce_s = v;
    }
    __syncthreads();

    // ---- phase 1: er (t<32) + proj (8 rows/wave in 2 batches of 4) ----
    if (t < MW) {
        float a2 = 0.f;
        const float4* fd4 = (const float4*)(fd + (size_t)(b * MM + m0 + t) * DD);
        const float4* ur4 = (const float4*)u_r;
#pragma unroll
        for (int k = 0; k < 16; ++k) {
            float4 f = fd4[k], u = ur4[k];
            a2 += f.x * u.x + f.y * u.y + f.z * u.z + f.w * u.w;
        }
        er_lds[t] = a2;
    }
#pragma unroll
    for (int it2 = 0; it2 < 2; ++it2) {
        int r0 = g * 8 + it2 * 4;
        float acc[4] = {0.f, 0.f, 0.f, 0.f};
#pragma unroll 4
        for (int k4 = 0; k4 < 16; ++k4) {
            float4 wk = wreg[k4];
#pragma unroll
            for (int rr = 0; rr < 4; ++rr) {
                float4 rv = ((const float4*)fsh)[(r0 + rr) * 16 + k4]; // bcast
                acc[rr] += rv.x * wk.x + rv.y * wk.y + rv.z * wk.z + rv.w * wk.w;
            }
        }
#pragma unroll
        for (int rr = 0; rr < 4; ++rr) {
            float e = acc[rr] * al;
#pragma unroll
            for (int off = 32; off > 0; off >>= 1) e += __shfl_xor(e, off, 64);
            if (lane == 0) el_lds[r0 + rr] = e;
        }
#pragma unroll
        for (int rr = 0; rr < 4; ++rr)     // rows fully consumed; overwrite
            fsh[(r0 + rr) * DD + lane] = acc[rr];
    }
    __syncthreads();

    // ---- phase 2: scores 32n x 32m ----
    {
        int m = t & 31, h = t >> 5;        // h in 0..7
        float ce = ce_s;
        float er_m = er_lds[m];
        const float* fe_p = fe + ((size_t)(b * NN + n0)) * MM + m0 + m;
        const int* adj_p = adj + ((size_t)(b * NN + n0)) * MM + m0 + m;
        float dsum = 0.f, fsum = 0.f;
#pragma unroll
        for (int j = 0; j < 4; ++j) {
            int n = h * 4 + j;
            float f = fe_p[(size_t)n * MM];
            int a = adj_p[(size_t)n * MM];
            float s = el_lds[n] + ce * f + er_m;
            s = s > 0.f ? s : NEG_SLOPE * s;
            float p = (a == 1) ? __expf(s) : 0.f;
            p_lds[n * PSTR + m] = p;
            dsum += p;
            fsum += f * p;
        }
        dred[h][m] = dsum;
        fred[h][m] = fsum;
    }
    __syncthreads();

    // ---- phase 3: aggregation; wave g owns m = g*8..g*8+7, lane owns d ----
    size_t obase = (((size_t)(b * NMT + mt)) * NCH + ch) * MW;
    {
        int d = lane;
        float acc8[8];
#pragma unroll
        for (int i = 0; i < 8; ++i) acc8[i] = 0.f;
#pragma unroll 4
        for (int n = 0; n < CH; ++n) {
            float hv = fsh[n * DD + d];
            float4 pa = *(const float4*)&p_lds[n * PSTR + g * 8];
            float4 pb = *(const float4*)&p_lds[n * PSTR + g * 8 + 4];
            acc8[0] += pa.x * hv; acc8[1] += pa.y * hv;
            acc8[2] += pa.z * hv; acc8[3] += pa.w * hv;
            acc8[4] += pb.x * hv; acc8[5] += pb.y * hv;
            acc8[6] += pb.z * hv; acc8[7] += pb.w * hv;
        }
#pragma unroll
        for (int mm = 0; mm < 8; ++mm)
            pacc[(obase + g * 8 + mm) * DD + d] = acc8[mm];
    }
    if (t < MW) {
        float dn = 0.f, sf = 0.f;
#pragma unroll
        for (int hh = 0; hh < 8; ++hh) { dn += dred[hh][t]; sf += fred[hh][t]; }
        size_t q2 = (obase + t) * 2;
        pdn[q2] = dn;
        pdn[q2 + 1] = sf;
    }
}

// ---------------------------------------------------------------------------
// K2: out[bm,d] = sigmoid((W_edge[d]*Σsfe + Σacc) / Σdenom) over 64 chunks
// ---------------------------------------------------------------------------
__global__ __launch_bounds__(256) void reduce_kernel(
        const float* __restrict__ pacc, const float* __restrict__ pdn,
        const float* __restrict__ W_edge, float* __restrict__ out) {
    int gid = blockIdx.x * 256 + threadIdx.x;   // 32768
    int d = gid & 63, bm = gid >> 6;
    int b = bm >> 7, m = bm & 127;
    int mt = m >> 5, ml = m & 31;
    size_t base = ((size_t)(b * NMT + mt)) * NCH;
    float accs = 0.f, dens = 0.f, sfes = 0.f;
#pragma unroll 8
    for (int ch = 0; ch < NCH; ++ch) {
        size_t idx = (base + ch) * MW + ml;
        accs += pacc[idx * DD + d];
        dens += pdn[idx * 2];
        sfes += pdn[idx * 2 + 1];
    }
    float v = (W_edge[d] * sfes + accs) / dens;
    out[(size_t)bm * DD + d] = 1.f / (1.f + __expf(-v));
}

extern "C" void kernel_launch(void* const* d_in, const int* in_sizes, int n_in,
                              void* d_out, int out_size, void* d_ws, size_t ws_size,
                              hipStream_t stream) {
    const float* feat_src  = (const float*)d_in[0];
    const float* feat_dst  = (const float*)d_in[1];
    const float* feat_edge = (const float*)d_in[2];
    const int*   adj       = (const int*)d_in[3];
    const float* W_src     = (const float*)d_in[4];
    const float* W_dst     = (const float*)d_in[5];
    const float* W_edge    = (const float*)d_in[6];
    const float* attn_l    = (const float*)d_in[7];
    const float* attn_r    = (const float*)d_in[8];
    const float* attn_e    = (const float*)d_in[9];
    float* out = (float*)d_out;

    float* ws   = (float*)d_ws;
    float* pacc = ws;                                   // 16*64*32*64 = 2097152
    float* pdn  = pacc + (size_t)BB * NMT * NCH * MW * DD;   // 131072

    fused_all_kernel<<<dim3(NCH, NMT, BB), 256, 0, stream>>>(
        feat_src, W_src, attn_l, feat_dst, W_dst, attn_r,
        W_edge, attn_e, feat_edge, adj, pacc, pdn);
    reduce_kernel<<<128, 256, 0, stream>>>(pacc, pdn, W_edge, out);
}

// Round 10
// 27.247 us; speedup vs baseline: 1.9201x; 1.9201x over previous
//
#include <hip/hip_runtime.h>
#include <math.h>

#define BB 4
#define NN 2048
#define MM 128
#define DD 64
#define NEG_SLOPE 0.2f

#define MT 16                 // m per fused block
#define NMT (MM / MT)         // 8 m-tiles
#define NSPL 16               // n splits
#define NR (NN / NSPL)        // 128 n per block
#define PSTR 132              // p_lds row stride (528B, 16B-aligned)

// ---------------------------------------------------------------------------
// proj_all (R3-proven): blocks 0..511: hs, el.  blocks 512,513: er, c_e.
// ---------------------------------------------------------------------------
__global__ __launch_bounds__(256) void proj_all_kernel(
        const float* __restrict__ fs, const float* __restrict__ W_src,
        const float* __restrict__ attn_l,
        const float* __restrict__ fd, const float* __restrict__ W_dst,
        const float* __restrict__ attn_r,
        const float* __restrict__ W_edge, const float* __restrict__ attn_e,
        float* __restrict__ hs, float* __restrict__ el,
        float* __restrict__ er, float* __restrict__ c_e) {
    int t = threadIdx.x;
    if (blockIdx.x < 512) {
        int lane = t & 63, w = t >> 6;
        int row0 = blockIdx.x * 16;
        __shared__ float4 rows4[16][16];
        const float4* fs4 = (const float4*)(fs + (size_t)row0 * DD);
        ((float4*)rows4)[t] = fs4[t];
        float4 wreg[16];
        const float4* w4 = (const float4*)(W_src + (size_t)lane * DD);
#pragma unroll
        for (int k = 0; k < 16; ++k) wreg[k] = w4[k];
        float al = attn_l[lane];
        __syncthreads();
        float acc[4] = {0.f, 0.f, 0.f, 0.f};
#pragma unroll
        for (int k = 0; k < 16; ++k) {
#pragma unroll
            for (int j = 0; j < 4; ++j) {
                float4 rv = rows4[w * 4 + j][k];
                acc[j] += rv.x * wreg[k].x + rv.y * wreg[k].y +
                          rv.z * wreg[k].z + rv.w * wreg[k].w;
            }
        }
#pragma unroll
        for (int j = 0; j < 4; ++j) {
            int row = row0 + w * 4 + j;
            hs[(size_t)row * DD + lane] = acc[j];
            float v = acc[j] * al;
            for (int off = 32; off > 0; off >>= 1) v += __shfl_xor(v, off, 64);
            if (lane == 0) el[row] = v;
        }
    } else {
        int eb = blockIdx.x - 512;
        __shared__ float u_r[DD];
        if (t < DD) {
            float a = 0.f;
            for (int d = 0; d < DD; ++d) a += attn_r[d] * W_dst[d * DD + t];
            u_r[t] = a;
        }
        if (eb == 0 && t >= 64 && t < 128) {
            int lane = t & 63;
            float v = W_edge[lane] * attn_e[lane];
            for (int off = 32; off > 0; off >>= 1) v += __shfl_xor(v, off, 64);
            if (lane == 0) *c_e = v;
        }
        __syncthreads();
        int i = eb * 256 + t;
        float acc = 0.f;
        const float4* fd4 = (const float4*)(fd + (size_t)i * DD);
        const float4* ur4 = (const float4*)u_r;
#pragma unroll
        for (int k = 0; k < 16; ++k) {
            float4 f = fd4[k], u = ur4[k];
            acc += f.x * u.x + f.y * u.y + f.z * u.z + f.w * u.w;
        }
        er[i] = acc;
    }
}

// ---------------------------------------------------------------------------
// fused: per (ns, mt, b). Stage hs chunk; scores p=exp(masked leaky);
// agg with 8m x 2d register blocking, 4-way n-split, LDS partial reduce.
// ---------------------------------------------------------------------------
__global__ __launch_bounds__(256, 3) void fused_attn_kernel(
        const float* __restrict__ fe, const int* __restrict__ adj,
        const float* __restrict__ hs, const float* __restrict__ el,
        const float* __restrict__ er, const float* __restrict__ c_e_p,
        float* __restrict__ pacc, float* __restrict__ pdn) {
    int ns = blockIdx.x, mt = blockIdx.y, b = blockIdx.z;
    int n0 = ns * NR, m0 = mt * MT;
    int t = threadIdx.x;

    __shared__ __align__(16) float hs_lds[NR * DD];        // 32 KB; reused
    __shared__ __align__(16) float p_lds[MT * PSTR];       // 8.25 KB
    __shared__ float el_lds[NR];
    __shared__ float dred[16][17], fred[16][17];

    // ---- stage hs + el ----
    const float4* hs4 = (const float4*)(hs + ((size_t)(b * NN + n0)) * DD);
#pragma unroll 4
    for (int k = 0; k < 8; ++k)
        ((float4*)hs_lds)[t + k * 256] = hs4[t + k * 256];
    if (t < NR) el_lds[t] = el[b * NN + n0 + t];

    // ---- scores: thread (m = t&15, h = t>>4), n = h + 16j ----
    {
        int m = t & 15, h = t >> 4;
        float ce = *c_e_p;
        float er_m = er[b * MM + m0 + m];
        const float* fe_p = fe + ((size_t)(b * NN + n0)) * MM + m0 + m;
        const int* adj_p = adj + ((size_t)(b * NN + n0)) * MM + m0 + m;
        float dsum = 0.f, fsum = 0.f;
        // el not yet visible before barrier? el_lds written this phase by
        // other threads -> must read el from global here instead.
        const float* el_g = el + b * NN + n0;
#pragma unroll 4
        for (int j = 0; j < 8; ++j) {
            int n = h + j * 16;
            float f = fe_p[(size_t)n * MM];
            int a = adj_p[(size_t)n * MM];
            float s = el_g[n] + ce * f + er_m;
            s = s > 0.f ? s : NEG_SLOPE * s;
            float p = (a == 1) ? __expf(s) : 0.f;
            p_lds[m * PSTR + n] = p;
            dsum += p;
            fsum += f * p;
        }
        dred[h][m] = dsum;
        fred[h][m] = fsum;
    }
    __syncthreads();

    // ---- agg: thread (nq = t>>6, mh = (t>>5)&1, dq = t&31) ----
    // acc[8 m][2 d] over its 32-n range; 12 LDS reads / 64 FMA per 4n.
    float acc[8][2];
    {
        int nq = t >> 6, mh = (t >> 5) & 1, dq = t & 31;
#pragma unroll
        for (int i = 0; i < 8; ++i) { acc[i][0] = 0.f; acc[i][1] = 0.f; }
        int rbase = mh * 8 * PSTR;
#pragma unroll 2
        for (int n4 = 0; n4 < 8; ++n4) {
            int nb = nq * 32 + n4 * 4;
            float2 h0 = *(const float2*)&hs_lds[(nb + 0) * DD + dq * 2];
            float2 h1 = *(const float2*)&hs_lds[(nb + 1) * DD + dq * 2];
            float2 h2 = *(const float2*)&hs_lds[(nb + 2) * DD + dq * 2];
            float2 h3 = *(const float2*)&hs_lds[(nb + 3) * DD + dq * 2];
#pragma unroll
            for (int mj = 0; mj < 8; ++mj) {
                float4 p4 = *(const float4*)&p_lds[rbase + mj * PSTR + nb];
                acc[mj][0] += p4.x * h0.x + p4.y * h1.x + p4.z * h2.x + p4.w * h3.x;
                acc[mj][1] += p4.x * h0.y + p4.y * h1.y + p4.z * h2.y + p4.w * h3.y;
            }
        }
    }
    __syncthreads();                       // all agg reads done

    // ---- partial write into hs_lds region: partials[nq][m][d] ----
    {
        int nq = t >> 6, mh = (t >> 5) & 1, dq = t & 31;
        float* part = hs_lds + nq * (MT * DD);
#pragma unroll
        for (int mj = 0; mj < 8; ++mj)
            *(float2*)&part[(mh * 8 + mj) * DD + dq * 2] =
                make_float2(acc[mj][0], acc[mj][1]);
    }
    __syncthreads();

    // ---- final: sum 4 partials, write pacc; pdn from dred/fred ----
    size_t pbase = (size_t)((b * NMT + mt) * NSPL + ns) * MT;
    {
        int m = t >> 4, ds = t & 15;       // d = ds*4
        float4 s0 = *(const float4*)&hs_lds[0 * MT * DD + m * DD + ds * 4];
        float4 s1 = *(const float4*)&hs_lds[1 * MT * DD + m * DD + ds * 4];
        float4 s2 = *(const float4*)&hs_lds[2 * MT * DD + m * DD + ds * 4];
        float4 s3 = *(const float4*)&hs_lds[3 * MT * DD + m * DD + ds * 4];
        float4 o;
        o.x = s0.x + s1.x + s2.x + s3.x;
        o.y = s0.y + s1.y + s2.y + s3.y;
        o.z = s0.z + s1.z + s2.z + s3.z;
        o.w = s0.w + s1.w + s2.w + s3.w;
        *(float4*)&pacc[(pbase + m) * DD + ds * 4] = o;
    }
    if (t < MT) {
        float ds2 = 0.f, fs2 = 0.f;
#pragma unroll
        for (int k = 0; k < 16; ++k) { ds2 += dred[k][t]; fs2 += fred[k][t]; }
        size_t q = (pbase + t) * 2;
        pdn[q] = ds2;
        pdn[q + 1] = fs2;
    }
}

// ---------------------------------------------------------------------------
// reduce: out[bm,d] = sigmoid((W_edge[d]*Σsfe + Σacc) / Σdenom)
// ---------------------------------------------------------------------------
__global__ __launch_bounds__(256) void reduce_kernel(
        const float* __restrict__ pacc, const float* __restrict__ pdn,
        const float* __restrict__ W_edge, float* __restrict__ out) {
    int gid = blockIdx.x * 256 + threadIdx.x;   // 32768
    int d = gid & 63, bm = gid >> 6;
    int b = bm >> 7, mm = bm & 127;
    int mt = mm >> 4, ml = mm & 15;
    size_t base = ((size_t)(b * NMT + mt)) * NSPL;
    float accs = 0.f, dens = 0.f, sfes = 0.f;
#pragma unroll
    for (int ns = 0; ns < NSPL; ++ns) {
        size_t idx = (base + ns) * MT + ml;
        accs += pacc[idx * DD + d];
        dens += pdn[idx * 2];
        sfes += pdn[idx * 2 + 1];
    }
    float v = (W_edge[d] * sfes + accs) / dens;
    out[(size_t)bm * DD + d] = 1.f / (1.f + __expf(-v));
}

extern "C" void kernel_launch(void* const* d_in, const int* in_sizes, int n_in,
                              void* d_out, int out_size, void* d_ws, size_t ws_size,
                              hipStream_t stream) {
    const float* feat_src  = (const float*)d_in[0];
    const float* feat_dst  = (const float*)d_in[1];
    const float* feat_edge = (const float*)d_in[2];
    const int*   adj       = (const int*)d_in[3];
    const float* W_src     = (const float*)d_in[4];
    const float* W_dst     = (const float*)d_in[5];
    const float* W_edge    = (const float*)d_in[6];
    const float* attn_l    = (const float*)d_in[7];
    const float* attn_r    = (const float*)d_in[8];
    const float* attn_e    = (const float*)d_in[9];
    float* out = (float*)d_out;

    float* ws   = (float*)d_ws;
    float* hs   = ws;                           // B*N*D = 524288
    float* el   = hs + (size_t)BB * NN * DD;    // 8192
    float* er   = el + BB * NN;                 // 512
    float* c_e  = er + BB * MM;                 // 1 (pad 64)
    float* pacc = c_e + 64;                     // 524288
    float* pdn  = pacc + (size_t)BB * NMT * NSPL * MT * DD;  // 16384

    proj_all_kernel<<<514, 256, 0, stream>>>(feat_src, W_src, attn_l,
                                             feat_dst, W_dst, attn_r,
                                             W_edge, attn_e, hs, el, er, c_e);
    fused_attn_kernel<<<dim3(NSPL, NMT, BB), 256, 0, stream>>>(
        feat_edge, adj, hs, el, er, c_e, pacc, pdn);
    reduce_kernel<<<128, 256, 0, stream>>>(pacc, pdn, W_edge, out);
}